// Round 16
// baseline (520.433 us; speedup 1.0000x reference)
//
#include <hip/hip_runtime.h>
#include <hip/hip_bf16.h>

typedef __attribute__((ext_vector_type(4))) float f32x4;
typedef __attribute__((ext_vector_type(8))) short s16x8;

#define SEQ 2048
#define DM  2048
#define NH  16
#define HD  128

__device__ __forceinline__ unsigned short f2b(float f){
  unsigned int u = __builtin_bit_cast(unsigned int, f);
  u += 0x7fffu + ((u >> 16) & 1u);
  return (unsigned short)(u >> 16);
}
__device__ __forceinline__ float b2f(unsigned short h){
  unsigned int u = ((unsigned int)h) << 16;
  return __builtin_bit_cast(float, u);
}
__device__ __forceinline__ f32x4 mfma16(s16x8 a, s16x8 b, f32x4 c){
  return __builtin_amdgcn_mfma_f32_16x16x32_bf16(a, b, c, 0, 0, 0);
}

// ---------------------------------------------------------------------------
// One-shot f32 -> bf16 conversion: x -> xb, [wq|wk|wv] -> wfused, wo -> wob.
// ---------------------------------------------------------------------------
__global__ __launch_bounds__(256)
void convert_kernel(const float* __restrict__ x,  const float* __restrict__ wq,
                    const float* __restrict__ wk, const float* __restrict__ wv,
                    const float* __restrict__ wo,
                    unsigned short* __restrict__ xb,
                    unsigned short* __restrict__ wfused,
                    unsigned short* __restrict__ wob)
{
  size_t e = ((size_t)blockIdx.x * 256 + threadIdx.x) * 8;
  const float* src; unsigned short* dst;
  if (e < 16777216){ src = x + e; dst = xb + e; }
  else if (e < 29360128){
    size_t o = e - 16777216;
    int sel = (int)(o >> 22);
    const float* w = sel == 0 ? wq : (sel == 1 ? wk : wv);
    src = w + (o & 4194303); dst = wfused + o;
  } else {
    size_t o = e - 29360128;
    src = wo + o; dst = wob + o;
  }
  float4 a = ((const float4*)src)[0];
  float4 b = ((const float4*)src)[1];
  s16x8 v;
  v[0]=(short)f2b(a.x); v[1]=(short)f2b(a.y); v[2]=(short)f2b(a.z); v[3]=(short)f2b(a.w);
  v[4]=(short)f2b(b.x); v[5]=(short)f2b(b.y); v[6]=(short)f2b(b.z); v[7]=(short)f2b(b.w);
  *(s16x8*)dst = v;
}

// ---------------------------------------------------------------------------
// Ring-2 GEMM, 2 blocks/CU (R12 structure with CORRECT launch bounds):
// 256x256 tile, BK=32, 64 K-tiles, 8 waves, 64KB static LDS (2 x 32KB slots).
// VGPR ~120 <= 128 and 2 x 64KB <= 160KB -> 2 blocks/CU co-resident; the
// per-tile vmcnt(0)+barrier drain is covered by the sibling block (m114).
// Involutive XOR swizzle both sides. XCD-resident B-strips.
// ---------------------------------------------------------------------------
template<int MODE>
__global__ __launch_bounds__(512, 1)
void gemm8(const unsigned short* __restrict__ A,
           const unsigned short* __restrict__ B,
           unsigned short* __restrict__ qr, unsigned short* __restrict__ kr,
           float* __restrict__ voutf, unsigned short* __restrict__ vt,
           float* __restrict__ outf, const int* __restrict__ sp)
{
  __shared__ __align__(16) char lds[65536];
  const int tid  = threadIdx.x;
  const int lane = tid & 63;
  const int w    = tid >> 6;           // 0..7
  const int wr   = w >> 2;             // 0..1  (M half)
  const int wc   = w & 3;              // 0..3  (N quarter)
  const int l15  = lane & 15;
  const int lhi  = lane >> 4;          // 0..3
  const int rq   = lhi << 2;

  // XCD-resident B-strips: MODE0 nb = 3x + j%3, MODE1 nb = x.
  int bid = blockIdx.x;
  int x8 = bid & 7, jb = bid >> 3;
  int mb, nb;
  if (MODE == 0){ nb = 3*x8 + (jb % 3); mb = jb / 3; }
  else          { nb = x8;              mb = jb; }
  const int m0 = mb * 256, n0 = nb * 256;

  const int sp0 = (MODE == 0) ? sp[0] : 0;

  const unsigned short* Abase = A + (size_t)m0 * 2048;
  const unsigned short* Bbase = B + (size_t)n0 * 2048;

  f32x4 accL[4][4] = {};   // M-frags 0-3
  f32x4 accH[4][4] = {};   // M-frags 4-7

  auto STAGE = [&](const unsigned short* gbase, int slotoff, int t){
    #pragma unroll
    for (int r2 = 0; r2 < 2; r2++){
      int p  = r2*8192 + w*1024 + (lane << 4);     // physical LDS offset
      int lo = p ^ (((p >> 7) & 3) << 4);          // logical (involution)
      int row = lo >> 6, colB = lo & 63;
      __builtin_amdgcn_global_load_lds(
        (const __attribute__((address_space(1))) void*)
          (gbase + (size_t)row*2048 + t*32 + (colB >> 1)),
        (__attribute__((address_space(3))) void*)(lds + slotoff + r2*8192 + w*1024),
        16, 0, 0);
    }
  };
  auto LDA = [&](const char* base, int i0, s16x8* dst){
    #pragma unroll
    for (int i = 0; i < 4; i++){
      int row = wr*128 + (i0 + i)*16 + l15;
      int off = row*64 + lhi*16;
      dst[i] = *(const s16x8*)(base + (off ^ (((row >> 1) & 3) << 4)));
    }
  };
  auto LDB = [&](const char* base, s16x8* dst){
    #pragma unroll
    for (int j2 = 0; j2 < 4; j2++){
      int row = wc*64 + j2*16 + l15;
      int off = row*64 + lhi*16;
      dst[j2] = *(const s16x8*)(base + (off ^ (((row >> 1) & 3) << 4)));
    }
  };
  auto MM = [&](s16x8* a, s16x8* b, f32x4 (&ac)[4][4]){
    __builtin_amdgcn_s_setprio(1);
    #pragma unroll
    for (int i = 0; i < 4; i++)
      #pragma unroll
      for (int j2 = 0; j2 < 4; j2++)
        ac[i][j2] = mfma16(a[i], b[j2], ac[i][j2]);
    __builtin_amdgcn_s_setprio(0);
  };

#define TILE(T, ISSUE) { \
    const int s_ = (T) & 1; \
    const char* base_ = lds + s_*32768; \
    if (ISSUE){ \
      int so_ = (s_ ^ 1)*32768; \
      STAGE(Abase, so_, (T)+1); \
      STAGE(Bbase, so_+16384, (T)+1); \
    } \
    s16x8 bfr[4], afL[4], afH[4]; \
    LDB(base_+16384, bfr); LDA(base_, 0, afL); LDA(base_, 4, afH); \
    MM(afL, bfr, accL); MM(afH, bfr, accH); \
    asm volatile("s_waitcnt vmcnt(0)" ::: "memory"); \
    __builtin_amdgcn_s_barrier(); }

  // ---- prologue: stage tile 0 ----
  STAGE(Abase, 0, 0); STAGE(Bbase, 16384, 0);
  asm volatile("s_waitcnt vmcnt(0)" ::: "memory");
  __builtin_amdgcn_s_barrier();

  for (int t = 0; t < 63; t++) TILE(t, 1);
  { // t = 63: last tile (slot 1), no staging, no trailing sync
    const char* base_ = lds + 32768;
    s16x8 bfr[4], afL[4], afH[4];
    LDB(base_+16384, bfr); LDA(base_, 0, afL); LDA(base_, 4, afH);
    MM(afL, bfr, accL); MM(afH, bfr, accH);
  }
#undef TILE

  // ======================= epilogues =======================
  if (MODE == 1){
    #pragma unroll
    for (int h2 = 0; h2 < 2; h2++){
      f32x4 (&ac)[4][4] = h2 ? accH : accL;
      int ibase = h2 * 4;
      #pragma unroll
      for (int i = 0; i < 4; i++)
        #pragma unroll
        for (int r = 0; r < 4; r++){
          int m = m0 + wr*128 + (ibase+i)*16 + rq + r;
          #pragma unroll
          for (int j2 = 0; j2 < 4; j2++)
            outf[(size_t)m*DM + n0 + wc*64 + j2*16 + l15] = ac[i][j2][r];
        }
    }
    return;
  }

  const int b  = m0 >> 11;
  const int s0 = m0 & 2047;

  if (nb < 16){
    // ---- RoPE Q/K epilogue with block-local LDS angle tables ----
    const bool isK = (nb >= 8);
    unsigned short* dqk = isK ? kr : qr;
    const int fbase = (nb & 7) * 128;
    const int odd = lane & 1;

    __syncthreads();   // all K-loop LDS reads done; reuse LDS for tables
    float2* T2 = (float2*)lds;             // [32 s_lo][128 f]  32KB
    float2* T1 = (float2*)(lds + 32768);   // [ 8 s_hi][128 f]   8KB
    for (int idx = tid; idx < 5120; idx += 512){
      int fl = idx & 127;
      float th = exp2f(-(float)(fbase + fl) * (13.287712379549449f / 1024.0f));
      float sn, cn;
      if (idx < 4096){
        __sincosf((float)(idx >> 7) * th, &sn, &cn);
        T2[idx] = make_float2(cn, sn);
      } else {
        int sh = (idx - 4096) >> 7;
        __sincosf((float)(sp0 + s0 + sh*32) * th, &sn, &cn);
        T1[idx - 4096] = make_float2(cn, sn);
      }
    }
    __syncthreads();

    #pragma unroll
    for (int h2 = 0; h2 < 2; h2++){
      f32x4 (&ac)[4][4] = h2 ? accH : accL;
      int ibase = h2 * 4;
      #pragma unroll
      for (int i = 0; i < 4; i++){
        #pragma unroll
        for (int r = 0; r < 4; r++){
          int srow = wr*128 + (ibase+i)*16 + rq + r;
          int s  = s0 + srow;
          int sh = srow >> 5, sl = srow & 31;
          #pragma unroll
          for (int j2 = 0; j2 < 4; j2++){
            float v  = ac[i][j2][r];
            float vx = __shfl_xor(v, 1);
            int nn_loc = wc*64 + j2*16 + l15;
            int fl = nn_loc >> 1;
            float2 a1 = T1[sh*128 + fl];
            float2 a2 = T2[sl*128 + fl];
            float cn = a1.x*a2.x - a1.y*a2.y;
            float sn = a1.y*a2.x + a1.x*a2.y;
            float x1 = odd ? vx : v;
            float x2 = odd ? v  : vx;
            float ov = odd ? (x1*sn + x2*cn) : (x1*cn - x2*sn);
            int c = fbase + fl + (odd ? 1024 : 0);
            size_t adr = ((size_t)(b*NH + (c >> 7))*SEQ + s)*HD + (c & 127);
            dqk[adr] = f2b(ov);
          }
        }
      }
    }
  } else {
    // ---- V epilogue: vout f32 (B,H,S,hd) + vt bf16 (B,H,hd,S) ----
    #pragma unroll
    for (int h2 = 0; h2 < 2; h2++){
      f32x4 (&ac)[4][4] = h2 ? accH : accL;
      int ibase = h2 * 4;
      #pragma unroll
      for (int i = 0; i < 4; i++){
        int sb = s0 + wr*128 + (ibase+i)*16 + rq;
        #pragma unroll
        for (int j2 = 0; j2 < 4; j2++){
          int d = (nb - 16)*256 + wc*64 + j2*16 + l15;
          int h = d >> 7, dd = d & 127;
          size_t vb = ((size_t)(b*NH + h)*SEQ + sb)*HD + dd;
          #pragma unroll
          for (int r = 0; r < 4; r++)
            voutf[vb + (size_t)r*HD] = ac[i][j2][r];
          ushort4 pk;
          pk.x = f2b(ac[i][j2][0]); pk.y = f2b(ac[i][j2][1]);
          pk.z = f2b(ac[i][j2][2]); pk.w = f2b(ac[i][j2][3]);
          *(ushort4*)(vt + ((size_t)(b*NH + h)*HD + dd)*SEQ + sb) = pk;
        }
      }
    }
  }
}

// ---------------------------------------------------------------------------
// Causal flash attention v4 + XCD co-location + fused kout upconvert
// (R15, unchanged).
// ---------------------------------------------------------------------------
__global__ __launch_bounds__(256)
void attn_kernel(const unsigned short* __restrict__ qr,
                 const unsigned short* __restrict__ kr,
                 const unsigned short* __restrict__ vt,
                 unsigned short* __restrict__ attnout,
                 float* __restrict__ koutf)
{
  const int L    = (int)blockIdx.x + 16 * (int)blockIdx.y;
  const int xcd  = L & 7;
  const int idx  = L >> 3;              // 0..127
  const int bh   = (xcd << 3) | (idx & 7);
  const int pair = idx >> 3;            // 0..15
  const int tid  = threadIdx.x;
  const int lane = tid & 63;
  const int w    = tid >> 6;

  __shared__ __align__(16) char Klds[64 * 256];    // 16KB
  __shared__ __align__(16) char Vlds[128 * 144];   // 18KB
  __shared__ __align__(16) char Plds[4][16 * 144]; // 9KB

  const int l15 = lane & 15;
  const int lhi = lane >> 4;
  const int rq  = lhi << 2;
  char* pw = &Plds[w][0];

  s16x8 ones;
  #pragma unroll
  for (int i = 0; i < 8; i++) ones[i] = (short)0x3F80;

  const int b = bh >> 4, h = bh & 15;

  for (int ph = 0; ph < 2; ph++){
    const int qtile = ph ? (31 - pair) : pair;
    const int q0w = qtile*64 + w*16;

    s16x8 qf[4];
    const unsigned short* qbase = qr + ((size_t)bh*SEQ + q0w + l15) * HD + lhi*8;
    #pragma unroll
    for (int c = 0; c < 4; c++) qf[c] = *(const s16x8*)(qbase + c*32);

    f32x4 o[8] = {};
    f32x4 osum = {};
    float mrow[4] = {-1e30f,-1e30f,-1e30f,-1e30f};

    const int ntiles = qtile + 1;
    for (int t = 0; t < ntiles; t++){
      const int kv0 = t * 64;
      __syncthreads();
      { // stage K tile (64 x 128 bf16, rows 256B, XOR swz (r&15)<<4)
        int r = tid >> 2, q4 = tid & 3;
        const unsigned short* src = kr + ((size_t)bh*SEQ + kv0 + r) * HD + q4*32;
        int sw = (r & 15) << 4;
        char* drow = Klds + r*256;
        #pragma unroll
        for (int k = 0; k < 4; k++)
          *(s16x8*)(drow + ((q4*64 + k*16) ^ sw)) = *(const s16x8*)(src + k*8);
      }
      { // stage V^T tile (128 d-rows x 64 kv, 144B pitch)
        int r = tid >> 1, h2 = tid & 1;
        const unsigned short* src = vt + ((size_t)bh*HD + r) * SEQ + kv0 + h2*32;
        char* drow = Vlds + r*144 + h2*64;
        #pragma unroll
        for (int k = 0; k < 4; k++)
          *(s16x8*)(drow + k*16) = *(const s16x8*)(src + k*8);
      }
      __syncthreads();

      // ---- S = Q K^T (16 q x 64 kv as four 16x16 tiles) ----
      f32x4 st[4];
      #pragma unroll
      for (int j = 0; j < 4; j++) st[j] = (f32x4){0.f,0.f,0.f,0.f};
      #pragma unroll
      for (int j = 0; j < 4; j++){
        int krw = j*16 + l15;
        int sw  = (krw & 15) << 4;
        #pragma unroll
        for (int c = 0; c < 4; c++){
          s16x8 kf = *(const s16x8*)(Klds + krw*256 + ((c*64 + lhi*16) ^ sw));
          st[j] = mfma16(qf[c], kf, st[j]);
        }
      }

      const float sc = 0.08838834764831845f;
      #pragma unroll
      for (int j = 0; j < 4; j++)
        #pragma unroll
        for (int r = 0; r < 4; r++){
          int qrow = q0w + rq + r;
          int kvc  = kv0 + j*16 + l15;
          st[j][r] = (kvc > qrow) ? -1e30f : st[j][r] * sc;
        }

      float mt[4];
      #pragma unroll
      for (int r = 0; r < 4; r++)
        mt[r] = fmaxf(fmaxf(st[0][r], st[1][r]), fmaxf(st[2][r], st[3][r]));
      #pragma unroll
      for (int mk = 1; mk < 16; mk <<= 1)
        #pragma unroll
        for (int r = 0; r < 4; r++) mt[r] = fmaxf(mt[r], __shfl_xor(mt[r], mk));

      int ok = 1;
      #pragma unroll
      for (int r = 0; r < 4; r++) ok &= (mt[r] <= mrow[r] + 8.0f) ? 1 : 0;
      if (!__all(ok)){
        float al[4];
        #pragma unroll
        for (int r = 0; r < 4; r++){
          float mn = fmaxf(mrow[r], mt[r]);
          al[r] = __expf(mrow[r] - mn);
          mrow[r] = mn;
        }
        #pragma unroll
        for (int c = 0; c < 8; c++)
          #pragma unroll
          for (int r = 0; r < 4; r++) o[c][r] *= al[r];
        #pragma unroll
        for (int r = 0; r < 4; r++) osum[r] *= al[r];
      }

      // ---- P = exp(S - m) -> per-wave LDS (144B pitch) ----
      #pragma unroll
      for (int r = 0; r < 4; r++){
        char* prb = pw + (rq + r)*144;
        #pragma unroll
        for (int j = 0; j < 4; j++){
          float p = __expf(st[j][r] - mrow[r]);
          *(unsigned short*)(prb + (j*16 + l15)*2) = f2b(p);
        }
      }

      asm volatile("s_waitcnt lgkmcnt(0)" ::: "memory");

      // ---- O += P V (two K=32 passes) ----
      #pragma unroll
      for (int ks = 0; ks < 2; ks++){
        s16x8 pa = *(const s16x8*)(pw + l15*144 + ks*64 + lhi*16);
        #pragma unroll
        for (int c = 0; c < 8; c++){
          int d = c*16 + l15;
          s16x8 vf = *(const s16x8*)(Vlds + d*144 + ks*64 + lhi*16);
          o[c] = mfma16(pa, vf, o[c]);
        }
        osum = mfma16(pa, ones, osum);
      }
    }

    // ---- epilogue: attn_out bf16 ----
    #pragma unroll
    for (int r = 0; r < 4; r++){
      float inv = 1.0f / osum[r];
      int s2 = q0w + rq + r;
      size_t base = ((size_t)(b*SEQ + s2)) * DM + h*HD;
      #pragma unroll
      for (int c = 0; c < 8; c++)
        attnout[base + c*16 + l15] = f2b(o[c][r] * inv);
    }

    // ---- kout f32 upconvert for this phase's 64 kr rows (coalesced) ----
    {
      const unsigned short* ksrc = kr + ((size_t)bh*SEQ + qtile*64)*HD;
      float* kdst = koutf + ((size_t)bh*SEQ + qtile*64)*HD;
      #pragma unroll
      for (int ch = 0; ch < 4; ch++){
        size_t e = (size_t)ch*2048 + tid*8;
        s16x8 v = *(const s16x8*)(ksrc + e);
        f32x4 a2, b2;
        #pragma unroll
        for (int i = 0; i < 4; i++){
          a2[i] = b2f((unsigned short)v[i]);
          b2[i] = b2f((unsigned short)v[i+4]);
        }
        *(f32x4*)(kdst + e)     = a2;
        *(f32x4*)(kdst + e + 4) = b2;
      }
    }
  }
}

// ---------------------------------------------------------------------------
extern "C" void kernel_launch(void* const* d_in, const int* in_sizes, int n_in,
                              void* d_out, int out_size, void* d_ws, size_t ws_size,
                              hipStream_t stream)
{
  const float* x  = (const float*)d_in[0];
  const float* wq = (const float*)d_in[1];
  const float* wk = (const float*)d_in[2];
  const float* wv = (const float*)d_in[3];
  const float* wo = (const float*)d_in[4];
  const int*   sp = (const int*)d_in[5];

  float* out  = (float*)d_out;            // (B,S,D) f32
  float* kout = out + 16777216;           // (B,H,S,hd) f32
  float* vout = out + 33554432;           // (B,H,S,hd) f32

  char* ws = (char*)d_ws;
  unsigned short* xb      = (unsigned short*)ws;                  // 8192x2048 bf16
  unsigned short* wfused  = (unsigned short*)(ws + 33554432);     // 6144x2048 bf16
  unsigned short* wob     = (unsigned short*)(ws + 58720256);     // 2048x2048 bf16
  unsigned short* qr      = (unsigned short*)(ws + 67108864);     // (B,H,S,hd) bf16
  unsigned short* kr      = (unsigned short*)(ws + 100663296);    // (B,H,S,hd) bf16
  unsigned short* vt      = (unsigned short*)(ws + 134217728);    // (B,H,hd,S) bf16
  unsigned short* attnout = (unsigned short*)ws;                  // alias xb

  // 1) f32 -> bf16 conversion
  convert_kernel<<<16384, 256, 0, stream>>>(x, wq, wk, wv, wo, xb, wfused, wob);
  // 2) fused QKV GEMM (ring-2, 2 blocks/CU, XCD B-strips)
  gemm8<0><<<768, 512, 0, stream>>>(xb, wfused, qr, kr,
                                    vout, vt, nullptr, sp);
  // 3) causal flash attention (v4 + XCD co-location + fused kout upconvert)
  attn_kernel<<<dim3(16, 64), 256, 0, stream>>>(qr, kr, vt, attnout, kout);
  // 4) output GEMM (ring-2, 2 blocks/CU)
  gemm8<1><<<256, 512, 0, stream>>>(attnout, wob, nullptr, nullptr,
                                    nullptr, nullptr, out, nullptr);
}

// Round 17
// 502.698 us; speedup vs baseline: 1.0353x; 1.0353x over previous
//
#include <hip/hip_runtime.h>
#include <hip/hip_bf16.h>

typedef __attribute__((ext_vector_type(4))) float f32x4;
typedef __attribute__((ext_vector_type(8))) short s16x8;

#define SEQ 2048
#define DM  2048
#define NH  16
#define HD  128

__device__ __forceinline__ unsigned short f2b(float f){
  unsigned int u = __builtin_bit_cast(unsigned int, f);
  u += 0x7fffu + ((u >> 16) & 1u);
  return (unsigned short)(u >> 16);
}
__device__ __forceinline__ float b2f(unsigned short h){
  unsigned int u = ((unsigned int)h) << 16;
  return __builtin_bit_cast(float, u);
}
__device__ __forceinline__ f32x4 mfma16(s16x8 a, s16x8 b, f32x4 c){
  return __builtin_amdgcn_mfma_f32_16x16x32_bf16(a, b, c, 0, 0, 0);
}

// ---------------------------------------------------------------------------
// One-shot f32 -> bf16 conversion: x -> xb, [wq|wk|wv] -> wfused, wo -> wob.
// ---------------------------------------------------------------------------
__global__ __launch_bounds__(256)
void convert_kernel(const float* __restrict__ x,  const float* __restrict__ wq,
                    const float* __restrict__ wk, const float* __restrict__ wv,
                    const float* __restrict__ wo,
                    unsigned short* __restrict__ xb,
                    unsigned short* __restrict__ wfused,
                    unsigned short* __restrict__ wob)
{
  size_t e = ((size_t)blockIdx.x * 256 + threadIdx.x) * 8;
  const float* src; unsigned short* dst;
  if (e < 16777216){ src = x + e; dst = xb + e; }
  else if (e < 29360128){
    size_t o = e - 16777216;
    int sel = (int)(o >> 22);
    const float* w = sel == 0 ? wq : (sel == 1 ? wk : wv);
    src = w + (o & 4194303); dst = wfused + o;
  } else {
    size_t o = e - 29360128;
    src = wo + o; dst = wob + o;
  }
  float4 a = ((const float4*)src)[0];
  float4 b = ((const float4*)src)[1];
  s16x8 v;
  v[0]=(short)f2b(a.x); v[1]=(short)f2b(a.y); v[2]=(short)f2b(a.z); v[3]=(short)f2b(a.w);
  v[4]=(short)f2b(b.x); v[5]=(short)f2b(b.y); v[6]=(short)f2b(b.z); v[7]=(short)f2b(b.w);
  *(s16x8*)dst = v;
}

// ---------------------------------------------------------------------------
// Ring-4 GEMM (R8 loop, best measured): 256x256 tile, BK=32, 64 K-tiles,
// 8 waves. LDS = 4 slots x 32KB, 3-deep prefetch, ONE s_barrier + vmcnt(8)
// per tile. Involutive XOR swizzle both sides. XCD-resident B-strips.
// MODE 0 rope epilogue writes qr/kr bf16 only (kout upconverted in attn).
// NOTE: 256^2 tile cannot co-reside (120 VGPR + 128 AGPR ~ 248 unified
// regs/wave -> 8 waves/CU max); ring-4 depth covers the drain instead.
// ---------------------------------------------------------------------------
template<int MODE>
__global__ __launch_bounds__(512, 1)
void gemm8(const unsigned short* __restrict__ A,
           const unsigned short* __restrict__ B,
           unsigned short* __restrict__ qr, unsigned short* __restrict__ kr,
           float* __restrict__ voutf, unsigned short* __restrict__ vt,
           float* __restrict__ outf, const int* __restrict__ sp)
{
  extern __shared__ char lds[];
  const int tid  = threadIdx.x;
  const int lane = tid & 63;
  const int w    = tid >> 6;           // 0..7
  const int wr   = w >> 2;             // 0..1  (M half)
  const int wc   = w & 3;              // 0..3  (N quarter)
  const int l15  = lane & 15;
  const int lhi  = lane >> 4;          // 0..3
  const int rq   = lhi << 2;

  // XCD-resident B-strips: MODE0 nb = 3x + j%3, MODE1 nb = x.
  int bid = blockIdx.x;
  int x8 = bid & 7, jb = bid >> 3;
  int mb, nb;
  if (MODE == 0){ nb = 3*x8 + (jb % 3); mb = jb / 3; }
  else          { nb = x8;              mb = jb; }
  const int m0 = mb * 256, n0 = nb * 256;

  const int sp0 = (MODE == 0) ? sp[0] : 0;

  const unsigned short* Abase = A + (size_t)m0 * 2048;
  const unsigned short* Bbase = B + (size_t)n0 * 2048;

  f32x4 accL[4][4] = {};   // M-frags 0-3
  f32x4 accH[4][4] = {};   // M-frags 4-7

  auto STAGE = [&](const unsigned short* gbase, int slotoff, int t){
    #pragma unroll
    for (int r2 = 0; r2 < 2; r2++){
      int p  = r2*8192 + w*1024 + (lane << 4);     // physical LDS offset
      int lo = p ^ (((p >> 7) & 3) << 4);          // logical (involution)
      int row = lo >> 6, colB = lo & 63;
      __builtin_amdgcn_global_load_lds(
        (const __attribute__((address_space(1))) void*)
          (gbase + (size_t)row*2048 + t*32 + (colB >> 1)),
        (__attribute__((address_space(3))) void*)(lds + slotoff + r2*8192 + w*1024),
        16, 0, 0);
    }
  };
  auto LDA = [&](const char* base, int i0, s16x8* dst){
    #pragma unroll
    for (int i = 0; i < 4; i++){
      int row = wr*128 + (i0 + i)*16 + l15;
      int off = row*64 + lhi*16;
      dst[i] = *(const s16x8*)(base + (off ^ (((row >> 1) & 3) << 4)));
    }
  };
  auto LDB = [&](const char* base, s16x8* dst){
    #pragma unroll
    for (int j2 = 0; j2 < 4; j2++){
      int row = wc*64 + j2*16 + l15;
      int off = row*64 + lhi*16;
      dst[j2] = *(const s16x8*)(base + (off ^ (((row >> 1) & 3) << 4)));
    }
  };
  auto MM = [&](s16x8* a, s16x8* b, f32x4 (&ac)[4][4]){
    __builtin_amdgcn_s_setprio(1);
    #pragma unroll
    for (int i = 0; i < 4; i++)
      #pragma unroll
      for (int j2 = 0; j2 < 4; j2++)
        ac[i][j2] = mfma16(a[i], b[j2], ac[i][j2]);
    __builtin_amdgcn_s_setprio(0);
  };

#define TILE(T, ISSUE, VMW) { \
    const int s_ = (T) & 3; \
    const char* base_ = lds + s_*32768; \
    if (ISSUE){ \
      int so_ = (((T)+3) & 3)*32768; \
      STAGE(Abase, so_, (T)+3); \
      STAGE(Bbase, so_+16384, (T)+3); \
    } \
    s16x8 bfr[4], afL[4], afH[4]; \
    LDB(base_+16384, bfr); LDA(base_, 0, afL); LDA(base_, 4, afH); \
    MM(afL, bfr, accL); MM(afH, bfr, accH); \
    asm volatile("s_waitcnt vmcnt(" #VMW ")" ::: "memory"); \
    __builtin_amdgcn_s_barrier(); }

  // ---- prologue: stage tiles 0,1,2; wait tile 0 ----
  STAGE(Abase, 0, 0);      STAGE(Bbase, 16384, 0);
  STAGE(Abase, 32768, 1);  STAGE(Bbase, 49152, 1);
  STAGE(Abase, 65536, 2);  STAGE(Bbase, 81920, 2);
  asm volatile("s_waitcnt vmcnt(8)" ::: "memory");
  __builtin_amdgcn_s_barrier();

  for (int t = 0; t < 61; t++) TILE(t, 1, 8);
  TILE(61, 0, 4);
  TILE(62, 0, 0);
  { // t = 63: last tile, no wait/barrier
    const char* base_ = lds + 3*32768;
    s16x8 bfr[4], afL[4], afH[4];
    LDB(base_+16384, bfr); LDA(base_, 0, afL); LDA(base_, 4, afH);
    MM(afL, bfr, accL); MM(afH, bfr, accH);
  }
#undef TILE

  // ======================= epilogues =======================
  if (MODE == 1){
    #pragma unroll
    for (int h2 = 0; h2 < 2; h2++){
      f32x4 (&ac)[4][4] = h2 ? accH : accL;
      int ibase = h2 * 4;
      #pragma unroll
      for (int i = 0; i < 4; i++)
        #pragma unroll
        for (int r = 0; r < 4; r++){
          int m = m0 + wr*128 + (ibase+i)*16 + rq + r;
          #pragma unroll
          for (int j2 = 0; j2 < 4; j2++)
            outf[(size_t)m*DM + n0 + wc*64 + j2*16 + l15] = ac[i][j2][r];
        }
    }
    return;
  }

  const int b  = m0 >> 11;
  const int s0 = m0 & 2047;

  if (nb < 16){
    // ---- RoPE Q/K epilogue with block-local LDS angle tables ----
    const bool isK = (nb >= 8);
    unsigned short* dqk = isK ? kr : qr;
    const int fbase = (nb & 7) * 128;
    const int odd = lane & 1;

    __syncthreads();   // all K-loop LDS reads done; reuse LDS for tables
    float2* T2 = (float2*)lds;             // [32 s_lo][128 f]
    float2* T1 = (float2*)(lds + 32768);   // [ 8 s_hi][128 f]
    for (int idx = tid; idx < 5120; idx += 512){
      int fl = idx & 127;
      float th = exp2f(-(float)(fbase + fl) * (13.287712379549449f / 1024.0f));
      float sn, cn;
      if (idx < 4096){
        __sincosf((float)(idx >> 7) * th, &sn, &cn);
        T2[idx] = make_float2(cn, sn);
      } else {
        int sh = (idx - 4096) >> 7;
        __sincosf((float)(sp0 + s0 + sh*32) * th, &sn, &cn);
        T1[idx - 4096] = make_float2(cn, sn);
      }
    }
    __syncthreads();

    #pragma unroll
    for (int h2 = 0; h2 < 2; h2++){
      f32x4 (&ac)[4][4] = h2 ? accH : accL;
      int ibase = h2 * 4;
      #pragma unroll
      for (int i = 0; i < 4; i++){
        #pragma unroll
        for (int r = 0; r < 4; r++){
          int srow = wr*128 + (ibase+i)*16 + rq + r;
          int s  = s0 + srow;
          int sh = srow >> 5, sl = srow & 31;
          #pragma unroll
          for (int j2 = 0; j2 < 4; j2++){
            float v  = ac[i][j2][r];
            float vx = __shfl_xor(v, 1);
            int nn_loc = wc*64 + j2*16 + l15;
            int fl = nn_loc >> 1;
            float2 a1 = T1[sh*128 + fl];
            float2 a2 = T2[sl*128 + fl];
            float cn = a1.x*a2.x - a1.y*a2.y;
            float sn = a1.y*a2.x + a1.x*a2.y;
            float x1 = odd ? vx : v;
            float x2 = odd ? v  : vx;
            float ov = odd ? (x1*sn + x2*cn) : (x1*cn - x2*sn);
            int c = fbase + fl + (odd ? 1024 : 0);
            size_t adr = ((size_t)(b*NH + (c >> 7))*SEQ + s)*HD + (c & 127);
            dqk[adr] = f2b(ov);
          }
        }
      }
    }
  } else {
    // ---- V epilogue: vout f32 (B,H,S,hd) + vt bf16 (B,H,hd,S) ----
    #pragma unroll
    for (int h2 = 0; h2 < 2; h2++){
      f32x4 (&ac)[4][4] = h2 ? accH : accL;
      int ibase = h2 * 4;
      #pragma unroll
      for (int i = 0; i < 4; i++){
        int sb = s0 + wr*128 + (ibase+i)*16 + rq;
        #pragma unroll
        for (int j2 = 0; j2 < 4; j2++){
          int d = (nb - 16)*256 + wc*64 + j2*16 + l15;
          int h = d >> 7, dd = d & 127;
          size_t vb = ((size_t)(b*NH + h)*SEQ + sb)*HD + dd;
          #pragma unroll
          for (int r = 0; r < 4; r++)
            voutf[vb + (size_t)r*HD] = ac[i][j2][r];
          ushort4 pk;
          pk.x = f2b(ac[i][j2][0]); pk.y = f2b(ac[i][j2][1]);
          pk.z = f2b(ac[i][j2][2]); pk.w = f2b(ac[i][j2][3]);
          *(ushort4*)(vt + ((size_t)(b*NH + h)*HD + dd)*SEQ + sb) = pk;
        }
      }
    }
  }
}

// ---------------------------------------------------------------------------
// Causal flash attention v4 + XCD co-location + fused kout upconvert.
// 4 waves x 16 q-rows, KVBLK=64, paired q-tiles {p, 31-p} (uniform load).
// Remap (pair,bh) so all 16 pair-blocks of one bh share an XCD -> KV
// working set stays L2-resident. Per phase, the block also upconverts its
// 64 kr rows -> kout f32 (coalesced, L2-warm).
// ---------------------------------------------------------------------------
__global__ __launch_bounds__(256)
void attn_kernel(const unsigned short* __restrict__ qr,
                 const unsigned short* __restrict__ kr,
                 const unsigned short* __restrict__ vt,
                 unsigned short* __restrict__ attnout,
                 float* __restrict__ koutf)
{
  const int L    = (int)blockIdx.x + 16 * (int)blockIdx.y;
  const int xcd  = L & 7;
  const int idx  = L >> 3;              // 0..127
  const int bh   = (xcd << 3) | (idx & 7);
  const int pair = idx >> 3;            // 0..15
  const int tid  = threadIdx.x;
  const int lane = tid & 63;
  const int w    = tid >> 6;

  __shared__ __align__(16) char Klds[64 * 256];    // 16KB
  __shared__ __align__(16) char Vlds[128 * 144];   // 18KB
  __shared__ __align__(16) char Plds[4][16 * 144]; // 9KB

  const int l15 = lane & 15;
  const int lhi = lane >> 4;
  const int rq  = lhi << 2;
  char* pw = &Plds[w][0];

  s16x8 ones;
  #pragma unroll
  for (int i = 0; i < 8; i++) ones[i] = (short)0x3F80;

  const int b = bh >> 4, h = bh & 15;

  for (int ph = 0; ph < 2; ph++){
    const int qtile = ph ? (31 - pair) : pair;
    const int q0w = qtile*64 + w*16;

    s16x8 qf[4];
    const unsigned short* qbase = qr + ((size_t)bh*SEQ + q0w + l15) * HD + lhi*8;
    #pragma unroll
    for (int c = 0; c < 4; c++) qf[c] = *(const s16x8*)(qbase + c*32);

    f32x4 o[8] = {};
    f32x4 osum = {};
    float mrow[4] = {-1e30f,-1e30f,-1e30f,-1e30f};

    const int ntiles = qtile + 1;
    for (int t = 0; t < ntiles; t++){
      const int kv0 = t * 64;
      __syncthreads();
      { // stage K tile (64 x 128 bf16, rows 256B, XOR swz (r&15)<<4)
        int r = tid >> 2, q4 = tid & 3;
        const unsigned short* src = kr + ((size_t)bh*SEQ + kv0 + r) * HD + q4*32;
        int sw = (r & 15) << 4;
        char* drow = Klds + r*256;
        #pragma unroll
        for (int k = 0; k < 4; k++)
          *(s16x8*)(drow + ((q4*64 + k*16) ^ sw)) = *(const s16x8*)(src + k*8);
      }
      { // stage V^T tile (128 d-rows x 64 kv, 144B pitch)
        int r = tid >> 1, h2 = tid & 1;
        const unsigned short* src = vt + ((size_t)bh*HD + r) * SEQ + kv0 + h2*32;
        char* drow = Vlds + r*144 + h2*64;
        #pragma unroll
        for (int k = 0; k < 4; k++)
          *(s16x8*)(drow + k*16) = *(const s16x8*)(src + k*8);
      }
      __syncthreads();

      // ---- S = Q K^T (16 q x 64 kv as four 16x16 tiles) ----
      f32x4 st[4];
      #pragma unroll
      for (int j = 0; j < 4; j++) st[j] = (f32x4){0.f,0.f,0.f,0.f};
      #pragma unroll
      for (int j = 0; j < 4; j++){
        int krw = j*16 + l15;
        int sw  = (krw & 15) << 4;
        #pragma unroll
        for (int c = 0; c < 4; c++){
          s16x8 kf = *(const s16x8*)(Klds + krw*256 + ((c*64 + lhi*16) ^ sw));
          st[j] = mfma16(qf[c], kf, st[j]);
        }
      }

      const float sc = 0.08838834764831845f;
      #pragma unroll
      for (int j = 0; j < 4; j++)
        #pragma unroll
        for (int r = 0; r < 4; r++){
          int qrow = q0w + rq + r;
          int kvc  = kv0 + j*16 + l15;
          st[j][r] = (kvc > qrow) ? -1e30f : st[j][r] * sc;
        }

      float mt[4];
      #pragma unroll
      for (int r = 0; r < 4; r++)
        mt[r] = fmaxf(fmaxf(st[0][r], st[1][r]), fmaxf(st[2][r], st[3][r]));
      #pragma unroll
      for (int mk = 1; mk < 16; mk <<= 1)
        #pragma unroll
        for (int r = 0; r < 4; r++) mt[r] = fmaxf(mt[r], __shfl_xor(mt[r], mk));

      int ok = 1;
      #pragma unroll
      for (int r = 0; r < 4; r++) ok &= (mt[r] <= mrow[r] + 8.0f) ? 1 : 0;
      if (!__all(ok)){
        float al[4];
        #pragma unroll
        for (int r = 0; r < 4; r++){
          float mn = fmaxf(mrow[r], mt[r]);
          al[r] = __expf(mrow[r] - mn);
          mrow[r] = mn;
        }
        #pragma unroll
        for (int c = 0; c < 8; c++)
          #pragma unroll
          for (int r = 0; r < 4; r++) o[c][r] *= al[r];
        #pragma unroll
        for (int r = 0; r < 4; r++) osum[r] *= al[r];
      }

      // ---- P = exp(S - m) -> per-wave LDS (144B pitch) ----
      #pragma unroll
      for (int r = 0; r < 4; r++){
        char* prb = pw + (rq + r)*144;
        #pragma unroll
        for (int j = 0; j < 4; j++){
          float p = __expf(st[j][r] - mrow[r]);
          *(unsigned short*)(prb + (j*16 + l15)*2) = f2b(p);
        }
      }

      asm volatile("s_waitcnt lgkmcnt(0)" ::: "memory");

      // ---- O += P V (two K=32 passes) ----
      #pragma unroll
      for (int ks = 0; ks < 2; ks++){
        s16x8 pa = *(const s16x8*)(pw + l15*144 + ks*64 + lhi*16);
        #pragma unroll
        for (int c = 0; c < 8; c++){
          int d = c*16 + l15;
          s16x8 vf = *(const s16x8*)(Vlds + d*144 + ks*64 + lhi*16);
          o[c] = mfma16(pa, vf, o[c]);
        }
        osum = mfma16(pa, ones, osum);
      }
    }

    // ---- epilogue: attn_out bf16 ----
    #pragma unroll
    for (int r = 0; r < 4; r++){
      float inv = 1.0f / osum[r];
      int s2 = q0w + rq + r;
      size_t base = ((size_t)(b*SEQ + s2)) * DM + h*HD;
      #pragma unroll
      for (int c = 0; c < 8; c++)
        attnout[base + c*16 + l15] = f2b(o[c][r] * inv);
    }

    // ---- kout f32 upconvert for this phase's 64 kr rows (coalesced) ----
    {
      const unsigned short* ksrc = kr + ((size_t)bh*SEQ + qtile*64)*HD;
      float* kdst = koutf + ((size_t)bh*SEQ + qtile*64)*HD;
      #pragma unroll
      for (int ch = 0; ch < 4; ch++){
        size_t e = (size_t)ch*2048 + tid*8;
        s16x8 v = *(const s16x8*)(ksrc + e);
        f32x4 a2, b2;
        #pragma unroll
        for (int i = 0; i < 4; i++){
          a2[i] = b2f((unsigned short)v[i]);
          b2[i] = b2f((unsigned short)v[i+4]);
        }
        *(f32x4*)(kdst + e)     = a2;
        *(f32x4*)(kdst + e + 4) = b2;
      }
    }
  }
}

// ---------------------------------------------------------------------------
extern "C" void kernel_launch(void* const* d_in, const int* in_sizes, int n_in,
                              void* d_out, int out_size, void* d_ws, size_t ws_size,
                              hipStream_t stream)
{
  const float* x  = (const float*)d_in[0];
  const float* wq = (const float*)d_in[1];
  const float* wk = (const float*)d_in[2];
  const float* wv = (const float*)d_in[3];
  const float* wo = (const float*)d_in[4];
  const int*   sp = (const int*)d_in[5];

  float* out  = (float*)d_out;            // (B,S,D) f32
  float* kout = out + 16777216;           // (B,H,S,hd) f32
  float* vout = out + 33554432;           // (B,H,S,hd) f32

  char* ws = (char*)d_ws;
  unsigned short* xb      = (unsigned short*)ws;                  // 8192x2048 bf16
  unsigned short* wfused  = (unsigned short*)(ws + 33554432);     // 6144x2048 bf16
  unsigned short* wob     = (unsigned short*)(ws + 58720256);     // 2048x2048 bf16
  unsigned short* qr      = (unsigned short*)(ws + 67108864);     // (B,H,S,hd) bf16
  unsigned short* kr      = (unsigned short*)(ws + 100663296);    // (B,H,S,hd) bf16
  unsigned short* vt      = (unsigned short*)(ws + 134217728);    // (B,H,hd,S) bf16
  unsigned short* attnout = (unsigned short*)ws;                  // alias xb

  hipFuncSetAttribute((const void*)gemm8<0>,
                      hipFuncAttributeMaxDynamicSharedMemorySize, 131072);
  hipFuncSetAttribute((const void*)gemm8<1>,
                      hipFuncAttributeMaxDynamicSharedMemorySize, 131072);

  // 1) f32 -> bf16 conversion
  convert_kernel<<<16384, 256, 0, stream>>>(x, wq, wk, wv, wo, xb, wfused, wob);
  // 2) fused QKV GEMM (ring-4, XCD B-strips)
  gemm8<0><<<768, 512, 131072, stream>>>(xb, wfused, qr, kr,
                                         vout, vt, nullptr, sp);
  // 3) causal flash attention (v4 + XCD co-location + fused kout upconvert)
  attn_kernel<<<dim3(16, 64), 256, 0, stream>>>(qr, kr, vt, attnout, kout);
  // 4) output GEMM (ring-4)
  gemm8<1><<<256, 512, 131072, stream>>>(attnout, wob, nullptr, nullptr,
                                         nullptr, nullptr, out, nullptr);
}